// Round 7
// baseline (133.484 us; speedup 1.0000x reference)
//
#include <hip/hip_runtime.h>
#include <hip/hip_bf16.h>
#include <math.h>
#include <stdint.h>

#define L_SEQ 4096
#define NB 2
#define NH 16
#define DHEAD 64
#define DM 1024
#define DQKV 3072

typedef __bf16 bf16_t;
typedef __attribute__((ext_vector_type(8))) __bf16 bf16x8;
typedef __attribute__((ext_vector_type(4))) float f32x4;

#define GLD16(gp, lp) __builtin_amdgcn_global_load_lds(                          \
    (const __attribute__((address_space(1))) void*)(gp),                         \
    (__attribute__((address_space(3))) void*)(lp), 16, 0, 0)

template<int N> __device__ __forceinline__ void vmwait() {
    if constexpr (N == 4)      asm volatile("s_waitcnt vmcnt(4)" ::: "memory");
    else if constexpr (N == 3) asm volatile("s_waitcnt vmcnt(3)" ::: "memory");
    else                       asm volatile("s_waitcnt vmcnt(0)" ::: "memory");
}

// ---------------- cast fp32 -> bf16, 8 elems/thread ----------------
__global__ __launch_bounds__(256) void cast_f2b_kernel(const float* __restrict__ in,
                                                       bf16_t* __restrict__ out, int n8)
{
    int t = blockIdx.x * 256 + threadIdx.x;
    if (t >= n8) return;
    const f32x4* ip = (const f32x4*)(in + (size_t)t * 8);
    f32x4 a = ip[0], b = ip[1];
    bf16x8 o;
    o[0] = (__bf16)a[0]; o[1] = (__bf16)a[1]; o[2] = (__bf16)a[2]; o[3] = (__bf16)a[3];
    o[4] = (__bf16)b[0]; o[5] = (__bf16)b[1]; o[6] = (__bf16)b[2]; o[7] = (__bf16)b[3];
    *(bf16x8*)(out + (size_t)t * 8) = o;
}

__global__ __launch_bounds__(256) void cast_w3_kernel(const float* __restrict__ wq,
                                                      const float* __restrict__ wk,
                                                      const float* __restrict__ wv,
                                                      bf16_t* __restrict__ out)
{
    int t = blockIdx.x * 256 + threadIdx.x;
    const int n1 = DM * DM / 8;
    const float* src; int lt;
    if (t < n1)          { src = wq; lt = t; }
    else if (t < 2 * n1) { src = wk; lt = t - n1; }
    else                 { src = wv; lt = t - 2 * n1; }
    const f32x4* ip = (const f32x4*)(src + (size_t)lt * 8);
    f32x4 a = ip[0], b = ip[1];
    bf16x8 o;
    o[0] = (__bf16)a[0]; o[1] = (__bf16)a[1]; o[2] = (__bf16)a[2]; o[3] = (__bf16)a[3];
    o[4] = (__bf16)b[0]; o[5] = (__bf16)b[1]; o[6] = (__bf16)b[2]; o[7] = (__bf16)b[3];
    *(bf16x8*)(out + (size_t)t * 8) = o;
}

// ---------------- conn[h][w]: per-head positional MLP + softmax ----------------
__device__ __forceinline__ float gelu_exact(float z)
{
    return 0.5f * z * (1.0f + erff(z * 0.7071067811865475f));
}

__global__ void conn_kernel(const float* __restrict__ cw1, const float* __restrict__ cb1,
                            const float* __restrict__ cw2, const float* __restrict__ cb2,
                            const float* __restrict__ cw3, const float* __restrict__ cb3,
                            float* __restrict__ conn)
{
    const int h = blockIdx.x;
    const int j = threadIdx.x;
    __shared__ float h1[7][32];
    __shared__ float h2[7][32];

    for (int w = 0; w < 7; ++w) {
        float pos = (float)w / 6.0f;
        float z = pos * cw1[h * 32 + j] + cb1[h * 32 + j];
        h1[w][j] = gelu_exact(z);
    }
    __syncthreads();
    for (int w = 0; w < 7; ++w) {
        float z = cb2[h * 32 + j];
        for (int i = 0; i < 32; ++i) z += h1[w][i] * cw2[((size_t)h * 32 + j) * 32 + i];
        h2[w][j] = gelu_exact(z);
    }
    __syncthreads();
    if (j == 0) {
        float cwt[7];
        float mx = -1e30f;
        for (int w = 0; w < 7; ++w) {
            float z = cb3[h];
            for (int i = 0; i < 32; ++i) z += h2[w][i] * cw3[h * 32 + i];
            cwt[w] = z;
            mx = fmaxf(mx, z);
        }
        float Z = 0.0f;
        for (int w = 0; w < 7; ++w) { cwt[w] = expf(cwt[w] - mx); Z += cwt[w]; }
        for (int w = 0; w < 7; ++w) conn[h * 7 + w] = cwt[w] / Z;
    }
}

// ---------------- 8-phase bf16 GEMM, corrected sync ledger ----------------
// C[M=8192, NOUT] = A @ Bw^T (+bias).  512 thr = 8 waves, GM M-groups x (8/GM) N-groups.
// BK=32, triple-buffered LDS; rows 64 B (4 x 16B slots), XOR-swizzle
// slot' = slot ^ ((row>>1)&3) (2-way banks = free; 0 conflicts measured in R5).
// Staging: every wave stages its 1024B slice of EVERY 8KB chunk (1 GLD16 each)
// => per-wave load count is uniform: NCH per tile.  Prefetch distance 2.
// SYNC LEDGER (per wave, all uniform):
//   prologue: stage t0, t1 (2*NCH) -> vmwait<NCH> (drains t0) -> s_barrier.
//   tile t: entry queue = [t+1's NCH] and tile t fully published.
//     ns=0: ds_reads(t) || stage chunks 0,1 of t+2 -> bar -> lgkm0 -> MFMA -> bar
//     ns=1: ds_reads(t) || stage chunks 2..NCH-1 of t+2;
//           gate: t<=NT-3 -> vmwait<NCH>  (queue [t+1 NCH, t+2 NCH] -> drains t+1)
//                 t==NT-2 -> vmwait<0>    (no t+2 staged; drains t+1 = last tile)
//                 t==NT-1 -> none
//           -> bar (publishes tile t+1) -> lgkm0 -> MFMA -> bar
// Reads always happen AFTER a barrier that followed every wave's drain of the
// tile being read (the R6 bug was reads between vmwait and barrier).
// LDS overwrite safety: stage(t+2) writes buf[(t-1)%3]; all tile t-1 ds_reads
// completed (lgkmcnt(0) before MFMA) before t-1's trailing barrier.
template<int BM, int BN, int GM, int NTN, int NOUT, bool F32OUT, bool BIAS>
__global__ __launch_bounds__(512, 2) void gemm8p(const bf16_t* __restrict__ A,
                                                 const bf16_t* __restrict__ Bw,
                                                 void* __restrict__ Cout,
                                                 const float* __restrict__ bias)
{
    constexpr int K      = 1024;
    constexpr int NT     = K / 32;             // 32 K-tiles
    constexpr int WAVE_M = BM / GM;
    constexpr int WAVE_N = BN / (8 / GM);
    constexpr int MI     = WAVE_M / 16;
    constexpr int NJ     = WAVE_N / 16;
    constexpr int NJH    = NJ / 2;
    constexpr int CA     = BM / 128;           // A chunks per tile
    constexpr int CB     = BN / 128;
    constexpr int NCH    = CA + CB;            // 3 or 4
    constexpr int ABUF   = BM * 64;
    constexpr int BBUF   = BN * 64;

    extern __shared__ char smem[];             // A: 3*ABUF @0; B: 3*BBUF @3*ABUF

    const int tid  = threadIdx.x, lane = tid & 63, wave = tid >> 6;
    const int mg   = (GM == 2) ? (wave & 1) : (wave & 3);
    const int ng   = (GM == 2) ? (wave >> 1) : (wave >> 2);
    const int wm   = mg * WAVE_M, wn = ng * WAVE_N;

    // T1: XCD-aware bijective swizzle (nwg == 256 in all launches)
    const int nwg = gridDim.x;
    int id = blockIdx.x;
    id = (id & 7) * (nwg >> 3) + (id >> 3);
    const int bm = (id / NTN) * BM;
    const int bn = (id % NTN) * BN;

    // staging: thread covers row tid>>2 (128 rows/chunk), 16B slot tid&3;
    // source col pre-swizzled: elem = ((tid&3) ^ ((row>>1)&3)) * 8, row=tid>>2
    const int srow = tid >> 2;
    const int sc   = ((tid & 3) ^ ((tid >> 3) & 3)) * 8;
    const bf16_t* Ag = A  + (size_t)(bm + srow) * K + sc;
    const bf16_t* Bg = Bw + (size_t)(bn + srow) * K + sc;
    const int wb = wave * 1024;

    auto stage_chunk = [&](int kt, int buf, int c) {
        if (c < CA)
            GLD16(Ag + (size_t)(c * 128) * K + kt * 32,
                  smem + buf * ABUF + c * 8192 + wb);
        else
            GLD16(Bg + (size_t)((c - CA) * 128) * K + kt * 32,
                  smem + 3 * ABUF + buf * BBUF + (c - CA) * 8192 + wb);
    };

    f32x4 acc[MI][NJ] = {};

#pragma unroll
    for (int c = 0; c < NCH; ++c) stage_chunk(0, 0, c);
#pragma unroll
    for (int c = 0; c < NCH; ++c) stage_chunk(1, 1, c);

    // swizzled read offsets: slot' = (lane>>4) ^ ((row>>1)&3), row bits 1-2 = lane bits 1-2
    int aoff[MI], boff[NJ];
    const int slot = (((lane >> 4) ^ ((lane >> 1) & 3)) * 16);
#pragma unroll
    for (int m = 0; m < MI; ++m) aoff[m] = (wm + m * 16 + (lane & 15)) * 64 + slot;
#pragma unroll
    for (int n = 0; n < NJ; ++n) boff[n] = (wn + n * 16 + (lane & 15)) * 64 + slot;

    vmwait<NCH>();                             // drain tile 0 (own loads)
    __builtin_amdgcn_s_barrier();              // publish tile 0 (all waves drained)

    int tb = 0, ts = 2;                        // LDS buf of tile t / tile t+2
    for (int t = 0; t < NT; ++t) {
        const char* Ab = smem + tb * ABUF;
        const char* Bb = smem + 3 * ABUF + tb * BBUF;
        const bool st = (t + 2 < NT);

        bf16x8 af[MI];
#pragma unroll
        for (int ns = 0; ns < 2; ++ns) {
            bf16x8 bf2[NJH];
            if (ns == 0) {
#pragma unroll
                for (int m = 0; m < MI; ++m) af[m] = *(const bf16x8*)(Ab + aoff[m]);
            }
#pragma unroll
            for (int j = 0; j < NJH; ++j) bf2[j] = *(const bf16x8*)(Bb + boff[ns * NJH + j]);

            if (st) {
                if (ns == 0) { stage_chunk(t + 2, ts, 0); stage_chunk(t + 2, ts, 1); }
                else {
                    stage_chunk(t + 2, ts, 2);
                    if (NCH == 4) stage_chunk(t + 2, ts, 3);
                }
            }
            if (ns == 1) {                     // gate for tile t+1 (see ledger)
                if (t <= NT - 3)      vmwait<NCH>();
                else if (t == NT - 2) vmwait<0>();
            }

            __builtin_amdgcn_s_barrier();
            asm volatile("s_waitcnt lgkmcnt(0)" ::: "memory");
            __builtin_amdgcn_sched_barrier(0);
            __builtin_amdgcn_s_setprio(1);
#pragma unroll
            for (int m = 0; m < MI; ++m)
#pragma unroll
                for (int j = 0; j < NJH; ++j)
                    acc[m][ns * NJH + j] = __builtin_amdgcn_mfma_f32_16x16x32_bf16(
                        af[m], bf2[j], acc[m][ns * NJH + j], 0, 0, 0);
            __builtin_amdgcn_s_setprio(0);
            __builtin_amdgcn_s_barrier();
        }
        tb = (tb == 2) ? 0 : tb + 1;
        ts = (ts == 2) ? 0 : ts + 1;
    }

    // epilogue: C/D frag layout col=lane&15, row=(lane>>4)*4+reg
    const int r0 = (lane >> 4) * 4;
    const int c0 = lane & 15;
#pragma unroll
    for (int m = 0; m < MI; ++m) {
#pragma unroll
        for (int n = 0; n < NJ; ++n) {
            const int col = bn + wn + n * 16 + c0;
            float bv = BIAS ? bias[col] : 0.0f;
#pragma unroll
            for (int r = 0; r < 4; ++r) {
                const int row = bm + wm + m * 16 + r0 + r;
                float v = acc[m][n][r] + bv;
                if (F32OUT) ((float*)Cout)[(size_t)row * NOUT + col] = v;
                else        ((bf16_t*)Cout)[(size_t)row * NOUT + col] = (__bf16)v;
            }
        }
    }
}

// ---------------- windowed attention: 8 threads per (b,h,l), one per d-chunk ----------------
__global__ __launch_bounds__(256) void attn_win_kernel(const bf16_t* __restrict__ QKV,
                                                       const float* __restrict__ conn,
                                                       bf16_t* __restrict__ AO)
{
    const int t  = threadIdx.x;
    const int ll = t >> 3;
    const int c  = t & 7;
    const int blk  = blockIdx.x;
    const int lblk = blk & (L_SEQ / 32 - 1);
    const int h    = (blk >> 7) & (NH - 1);
    const int b    = blk >> 11;
    const int l    = lblk * 32 + ll;
    const size_t row = (size_t)b * L_SEQ + l;

    const bf16x8 qv = *(const bf16x8*)(QKV + row * DQKV + h * DHEAD + c * 8);

    float s[7];
#pragma unroll
    for (int o = 0; o < 7; ++o) {
        const int lk = l + o - 3;
        float d = 0.0f;
        if ((unsigned)lk < L_SEQ) {
            const bf16x8 kv = *(const bf16x8*)(QKV + ((size_t)b * L_SEQ + lk) * DQKV
                                               + DM + h * DHEAD + c * 8);
#pragma unroll
            for (int j = 0; j < 8; ++j) d += (float)qv[j] * (float)kv[j];
        }
        s[o] = d;
    }
#pragma unroll
    for (int m = 1; m < 8; m <<= 1) {
#pragma unroll
        for (int o = 0; o < 7; ++o) s[o] += __shfl_xor(s[o], m, 64);
    }

    float mx = -1e30f;
#pragma unroll
    for (int o = 0; o < 7; ++o) { s[o] *= 0.125f; mx = fmaxf(mx, s[o]); }
    float e[7], Z = 0.0f;
#pragma unroll
    for (int o = 0; o < 7; ++o) { e[o] = expf(s[o] - mx); Z += e[o]; }

    float fw[7], fs = 0.0f;
#pragma unroll
    for (int o = 0; o < 7; ++o) { fw[o] = e[o] * conn[h * 7 + o]; fs += fw[o]; }
    const float inv = 1.0f / (fs + 1e-9f * Z);

    float outv[8] = {};
#pragma unroll
    for (int o = 0; o < 7; ++o) {
        const int lk = l + o - 3;
        if ((unsigned)lk >= L_SEQ) continue;
        const float w = fw[o] * inv;
        const bf16x8 vv = *(const bf16x8*)(QKV + ((size_t)b * L_SEQ + lk) * DQKV
                                           + 2 * DM + h * DHEAD + c * 8);
#pragma unroll
        for (int j = 0; j < 8; ++j) outv[j] += w * (float)vv[j];
    }

    bf16x8 ov;
#pragma unroll
    for (int j = 0; j < 8; ++j) ov[j] = (__bf16)outv[j];
    *(bf16x8*)(AO + row * DM + h * DHEAD + c * 8) = ov;
}

// ---------------- launch ----------------
extern "C" void kernel_launch(void* const* d_in, const int* in_sizes, int n_in,
                              void* d_out, int out_size, void* d_ws, size_t ws_size,
                              hipStream_t stream)
{
    const float* x   = (const float*)d_in[0];
    const float* wq  = (const float*)d_in[1];
    const float* wk  = (const float*)d_in[2];
    const float* wv  = (const float*)d_in[3];
    const float* wo  = (const float*)d_in[4];
    const float* bo  = (const float*)d_in[5];
    const float* cw1 = (const float*)d_in[6];
    const float* cb1 = (const float*)d_in[7];
    const float* cw2 = (const float*)d_in[8];
    const float* cb2 = (const float*)d_in[9];
    const float* cw3 = (const float*)d_in[10];
    const float* cb3 = (const float*)d_in[11];
    float* out = (float*)d_out;

    char* ws = (char*)d_ws;
    const size_t MB = 1024 * 1024;
    bf16_t* xb    = (bf16_t*)(ws);             // 16 MB; reused as attention output
    bf16_t* wqkvb = (bf16_t*)(ws + 16 * MB);   // 6 MB   [3072][1024]
    bf16_t* wob   = (bf16_t*)(ws + 22 * MB);   // 2 MB
    bf16_t* QKV   = (bf16_t*)(ws + 24 * MB);   // 48 MB  [8192][3072]
    float*  conn  = (float*)(ws + 72 * MB);    // 448 B

    const int Mrows = NB * L_SEQ;              // 8192

    (void)hipFuncSetAttribute((const void*)gemm8p<256, 256, 2, 8, DQKV, false, false>,
                              hipFuncAttributeMaxDynamicSharedMemorySize, 98304);
    (void)hipFuncSetAttribute((const void*)gemm8p<256, 128, 4, 8, DQKV, false, false>,
                              hipFuncAttributeMaxDynamicSharedMemorySize, 73728);
    (void)hipFuncSetAttribute((const void*)gemm8p<128, 256, 2, 4, DM, true, true>,
                              hipFuncAttributeMaxDynamicSharedMemorySize, 73728);

    cast_f2b_kernel<<<(Mrows * DM / 8 + 255) / 256, 256, 0, stream>>>(x, xb, Mrows * DM / 8);
    cast_w3_kernel<<<(3 * DM * DM / 8) / 256, 256, 0, stream>>>(wq, wk, wv, wqkvb);
    cast_f2b_kernel<<<(DM * DM / 8 + 255) / 256, 256, 0, stream>>>(wo, wob, DM * DM / 8);

    conn_kernel<<<NH, 32, 0, stream>>>(cw1, cb1, cw2, cb2, cw3, cb3, conn);

    // QKV cols 0..2047: 32x8 = 256 blocks, 256x256 tiles (1 exact round)
    gemm8p<256, 256, 2, 8, DQKV, false, false><<<256, 512, 98304, stream>>>(
        xb, wqkvb, QKV, nullptr);
    // QKV cols 2048..3071: 32x8 = 256 blocks, 256x128 tiles (1 exact round)
    gemm8p<256, 128, 4, 8, DQKV, false, false><<<256, 512, 73728, stream>>>(
        xb, wqkvb + (size_t)2048 * DM, QKV + 2048, nullptr);

    attn_win_kernel<<<(NB * NH * L_SEQ * 8) / 256, 256, 0, stream>>>(QKV, conn, xb);

    // out-proj: 64x4 = 256 blocks, 128x256 tiles (1 exact round)
    gemm8p<128, 256, 2, 4, DM, true, true><<<256, 512, 73728, stream>>>(xb, wob, out, bo);
}

// Round 8
// 121.810 us; speedup vs baseline: 1.0958x; 1.0958x over previous
//
#include <hip/hip_runtime.h>
#include <hip/hip_bf16.h>
#include <math.h>
#include <stdint.h>

#define L_SEQ 4096
#define NB 2
#define NH 16
#define DHEAD 64
#define DM 1024
#define DQKV 3072

typedef __bf16 bf16_t;
typedef __attribute__((ext_vector_type(8))) __bf16 bf16x8;
typedef __attribute__((ext_vector_type(4))) float f32x4;

#define GLD16(gp, lp) __builtin_amdgcn_global_load_lds(                          \
    (const __attribute__((address_space(1))) void*)(gp),                         \
    (__attribute__((address_space(3))) void*)(lp), 16, 0, 0)

template<int N> __device__ __forceinline__ void vmwait() {
    if constexpr (N == 3)      asm volatile("s_waitcnt vmcnt(3)" ::: "memory");
    else if constexpr (N == 2) asm volatile("s_waitcnt vmcnt(2)" ::: "memory");
    else                       asm volatile("s_waitcnt vmcnt(0)" ::: "memory");
}

// ---------------- fused fp32->bf16 casts: x | wq|wk|wv | wo ----------------
__device__ __forceinline__ void cast8(const float* src, bf16_t* dst)
{
    const f32x4* ip = (const f32x4*)src;
    f32x4 a = ip[0], b = ip[1];
    bf16x8 o;
    o[0] = (__bf16)a[0]; o[1] = (__bf16)a[1]; o[2] = (__bf16)a[2]; o[3] = (__bf16)a[3];
    o[4] = (__bf16)b[0]; o[5] = (__bf16)b[1]; o[6] = (__bf16)b[2]; o[7] = (__bf16)b[3];
    *(bf16x8*)dst = o;
}

__global__ __launch_bounds__(256) void fused_cast_kernel(
    const float* __restrict__ x,  const float* __restrict__ wq,
    const float* __restrict__ wk, const float* __restrict__ wv,
    const float* __restrict__ wo,
    bf16_t* __restrict__ xb, bf16_t* __restrict__ wqkvb, bf16_t* __restrict__ wob)
{
    const int bid = blockIdx.x;
    const int tid = threadIdx.x;
    const int nW = DM * DM / 8;                          // 131072 chunks per weight
    if (bid < 4096) {                                    // x: 8192*1024/8 = 1,048,576 chunks
        int t = bid * 256 + tid;
        cast8(x + (size_t)t * 8, xb + (size_t)t * 8);
    } else if (bid < 4096 + 1536) {                      // wq|wk|wv -> [3072][1024]
        int t = (bid - 4096) * 256 + tid;
        const float* src; int lt;
        if (t < nW)          { src = wq; lt = t; }
        else if (t < 2 * nW) { src = wk; lt = t - nW; }
        else                 { src = wv; lt = t - 2 * nW; }
        cast8(src + (size_t)lt * 8, wqkvb + (size_t)t * 8);
    } else {                                             // wo: 512 blocks
        int t = (bid - 4096 - 1536) * 256 + tid;
        cast8(wo + (size_t)t * 8, wob + (size_t)t * 8);
    }
}

// ---------------- conn[h][w]: per-head positional MLP + softmax ----------------
__device__ __forceinline__ float gelu_exact(float z)
{
    return 0.5f * z * (1.0f + erff(z * 0.7071067811865475f));
}

__global__ void conn_kernel(const float* __restrict__ cw1, const float* __restrict__ cb1,
                            const float* __restrict__ cw2, const float* __restrict__ cb2,
                            const float* __restrict__ cw3, const float* __restrict__ cb3,
                            float* __restrict__ conn)
{
    const int h = blockIdx.x;
    const int j = threadIdx.x;
    __shared__ float h1[7][32];
    __shared__ float h2[7][32];

    for (int w = 0; w < 7; ++w) {
        float pos = (float)w / 6.0f;
        float z = pos * cw1[h * 32 + j] + cb1[h * 32 + j];
        h1[w][j] = gelu_exact(z);
    }
    __syncthreads();
    for (int w = 0; w < 7; ++w) {
        float z = cb2[h * 32 + j];
        for (int i = 0; i < 32; ++i) z += h1[w][i] * cw2[((size_t)h * 32 + j) * 32 + i];
        h2[w][j] = gelu_exact(z);
    }
    __syncthreads();
    if (j == 0) {
        float cwt[7];
        float mx = -1e30f;
        for (int w = 0; w < 7; ++w) {
            float z = cb3[h];
            for (int i = 0; i < 32; ++i) z += h2[w][i] * cw3[h * 32 + i];
            cwt[w] = z;
            mx = fmaxf(mx, z);
        }
        float Z = 0.0f;
        for (int w = 0; w < 7; ++w) { cwt[w] = expf(cwt[w] - mx); Z += cwt[w]; }
        for (int w = 0; w < 7; ++w) conn[h * 7 + w] = cwt[w] / Z;
    }
}

// ---------------- BMxBN bf16 GEMM, BK=32, triple-buffer (R5-proven) ----------------
// C[M=8192, NOUT] = A @ Bw^T (+bias).  512 thr = 8 waves as 4M x 2N.
// Per K-tile t: vmcnt(L) -> s_barrier -> 8 ds_read_b128 -> stage tile t+2 ->
// setprio(1) 16 MFMA setprio(0).  Swizzle: dest 16B slot sd holds source slot
// sd^((row>>1)&3); reads use slot^((row>>1)&3) => 2-way banks (measured 0 conflicts).
template<int BM, int BN, int NOUT, bool F32OUT, bool BIAS>
__global__ __launch_bounds__(512, 4) void gemm_fp(const bf16_t* __restrict__ A,
                                                  const bf16_t* __restrict__ Bw,
                                                  void* __restrict__ Cout,
                                                  const float* __restrict__ bias)
{
    constexpr int K   = 1024;
    constexpr int NT  = K / 32;
    constexpr int MI  = BM / 64;
    constexpr int NJ  = BN / 32;
    constexpr int LA  = BM / 128;
    constexpr int LB  = BN / 128;
    constexpr int L   = LA + LB;
    constexpr int ASZ = BM * 64;
    constexpr int BSZ = BN * 64;
    constexpr int NTN = NOUT / BN;

    extern __shared__ char smem[];

    const int tid  = threadIdx.x;
    const int lane = tid & 63;
    const int wave = tid >> 6;
    const int wm   = (wave >> 1) * (BM / 4);
    const int wn   = (wave & 1) * (BN / 2);

    const int nwg = gridDim.x;
    int id = blockIdx.x;
    id = (id & 7) * (nwg >> 3) + (id >> 3);
    const int bm = (id / NTN) * BM;
    const int bn = (id % NTN) * BN;

    const int scol = (((tid & 3) ^ ((tid >> 3) & 3)) * 8);
    const int srow = tid >> 2;
    const bf16_t* Ag = A  + (size_t)(bm + srow) * K + scol;
    const bf16_t* Bg = Bw + (size_t)(bn + srow) * K + scol;

    auto stage = [&](int kt) {
        char* la = smem + (kt % 3) * ASZ + tid * 16;
#pragma unroll
        for (int bl = 0; bl < LA; ++bl)
            GLD16(Ag + (size_t)(bl * 128) * K + kt * 32, la + bl * 8192);
        char* lb = smem + 3 * ASZ + (kt % 3) * BSZ + tid * 16;
#pragma unroll
        for (int bl = 0; bl < LB; ++bl)
            GLD16(Bg + (size_t)(bl * 128) * K + kt * 32, lb + bl * 8192);
    };

    f32x4 acc[MI][NJ] = {};

    stage(0); stage(1);

    int aoff[MI], boff[NJ];
#pragma unroll
    for (int m = 0; m < MI; ++m) {
        const int r = wm + m * 16 + (lane & 15);
        aoff[m] = r * 64 + (((lane >> 4) ^ ((r >> 1) & 3)) * 16);
    }
#pragma unroll
    for (int n = 0; n < NJ; ++n) {
        const int r = wn + n * 16 + (lane & 15);
        boff[n] = r * 64 + (((lane >> 4) ^ ((r >> 1) & 3)) * 16);
    }

    for (int t = 0; t < NT; ++t) {
        if (t < NT - 1) vmwait<L>(); else vmwait<0>();
        __builtin_amdgcn_s_barrier();
        asm volatile("" ::: "memory");

        const char* Ab = smem + (t % 3) * ASZ;
        const char* Bb = smem + 3 * ASZ + (t % 3) * BSZ;

        bf16x8 af[MI], bfr[NJ];
#pragma unroll
        for (int m = 0; m < MI; ++m) af[m]  = *(const bf16x8*)(Ab + aoff[m]);
#pragma unroll
        for (int n = 0; n < NJ; ++n) bfr[n] = *(const bf16x8*)(Bb + boff[n]);

        if (t + 2 < NT) {
            __builtin_amdgcn_sched_barrier(0);
            stage(t + 2);
        }

        __builtin_amdgcn_s_setprio(1);
#pragma unroll
        for (int m = 0; m < MI; ++m)
#pragma unroll
            for (int n = 0; n < NJ; ++n)
                acc[m][n] = __builtin_amdgcn_mfma_f32_16x16x32_bf16(af[m], bfr[n], acc[m][n], 0, 0, 0);
        __builtin_amdgcn_s_setprio(0);
    }

    const int r0 = (lane >> 4) * 4;
    const int c0 = lane & 15;
#pragma unroll
    for (int m = 0; m < MI; ++m) {
#pragma unroll
        for (int n = 0; n < NJ; ++n) {
            const int col = bn + wn + n * 16 + c0;
            float bv = BIAS ? bias[col] : 0.0f;
#pragma unroll
            for (int r = 0; r < 4; ++r) {
                const int row = bm + wm + m * 16 + r0 + r;
                float v = acc[m][n][r] + bv;
                if (F32OUT) ((float*)Cout)[(size_t)row * NOUT + col] = v;
                else        ((bf16_t*)Cout)[(size_t)row * NOUT + col] = (__bf16)v;
            }
        }
    }
}

// ---------------- windowed attention, LDS-staged K/V ----------------
// One block per (b, h, 128-l-chunk): grid = 2*16*32 = 1024, 256 threads.
// K/V rows [l0-3, l0+130] (135 rows) staged in LDS, row stride 72 elems
// (144 B = 9 x 16B -> ds_*_b128 aligned; +4 banks/row -> conflict-free for
// the 8-rows x 8-slots wave read pattern).  OOB rows stage zeros, which
// reproduces the reference's zero-pad semantics (score 0, V contribution 0).
#define LCH 128
#define KROWS (LCH + 7)
#define RSTR 72

__global__ __launch_bounds__(256) void attn_win_kernel(const bf16_t* __restrict__ QKV,
                                                       const float* __restrict__ conn,
                                                       bf16_t* __restrict__ AO)
{
    __shared__ bf16_t Kl[KROWS * RSTR];
    __shared__ bf16_t Vl[KROWS * RSTR];

    const int tid = threadIdx.x;
    const int blk = blockIdx.x;
    const int lc  = blk & 31;
    const int h   = (blk >> 5) & (NH - 1);
    const int b   = blk >> 9;
    const int l0  = lc * LCH;
    const size_t baseK = (size_t)b * L_SEQ * DQKV + DM + h * DHEAD;
    const size_t baseV = baseK + DM;

    // stage: 135 rows x 8 chunks = 1080 slots; 5 passes of 256 threads
#pragma unroll
    for (int it = 0; it < 5; ++it) {
        const int idx = it * 256 + tid;
        if (idx >= KROWS * 8) break;
        const int row = idx >> 3, c = idx & 7;
        const int l = l0 - 3 + row;
        bf16x8 kv = {}, vv = {};
        if ((unsigned)l < L_SEQ) {
            kv = *(const bf16x8*)(QKV + baseK + (size_t)l * DQKV + c * 8);
            vv = *(const bf16x8*)(QKV + baseV + (size_t)l * DQKV + c * 8);
        }
        *(bf16x8*)(Kl + row * RSTR + c * 8) = kv;
        *(bf16x8*)(Vl + row * RSTR + c * 8) = vv;
    }
    __syncthreads();

    const int ll = tid >> 3;          // 0..31
    const int c  = tid & 7;           // d-chunk

#pragma unroll
    for (int q = 0; q < LCH / 32; ++q) {
        const int lrow = ll + q * 32;            // local l in [0,128)
        const int l    = l0 + lrow;
        const size_t row = (size_t)b * L_SEQ + l;

        const bf16x8 qv = *(const bf16x8*)(QKV + row * DQKV + h * DHEAD + c * 8);

        float s[7];
#pragma unroll
        for (int o = 0; o < 7; ++o) {
            const bf16x8 kv = *(const bf16x8*)(Kl + (lrow + o) * RSTR + c * 8);
            float d = 0.0f;
#pragma unroll
            for (int j = 0; j < 8; ++j) d += (float)qv[j] * (float)kv[j];
            s[o] = d;
        }
#pragma unroll
        for (int m = 1; m < 8; m <<= 1) {
#pragma unroll
            for (int o = 0; o < 7; ++o) s[o] += __shfl_xor(s[o], m, 64);
        }

        float mx = -1e30f;
#pragma unroll
        for (int o = 0; o < 7; ++o) { s[o] *= 0.125f; mx = fmaxf(mx, s[o]); }
        float e[7], Z = 0.0f;
#pragma unroll
        for (int o = 0; o < 7; ++o) { e[o] = expf(s[o] - mx); Z += e[o]; }

        // fw = (e/Z)*conn; fw /= (sum(fw)+1e-9)  ==  e*conn / (sum(e*conn) + 1e-9*Z)
        float fw[7], fs = 0.0f;
#pragma unroll
        for (int o = 0; o < 7; ++o) { fw[o] = e[o] * conn[h * 7 + o]; fs += fw[o]; }
        const float inv = 1.0f / (fs + 1e-9f * Z);

        float outv[8] = {};
#pragma unroll
        for (int o = 0; o < 7; ++o) {
            const float w = fw[o] * inv;
            const bf16x8 vv = *(const bf16x8*)(Vl + (lrow + o) * RSTR + c * 8);
#pragma unroll
            for (int j = 0; j < 8; ++j) outv[j] += w * (float)vv[j];
        }

        bf16x8 ov;
#pragma unroll
        for (int j = 0; j < 8; ++j) ov[j] = (__bf16)outv[j];
        *(bf16x8*)(AO + row * DM + h * DHEAD + c * 8) = ov;
    }
}

// ---------------- launch ----------------
extern "C" void kernel_launch(void* const* d_in, const int* in_sizes, int n_in,
                              void* d_out, int out_size, void* d_ws, size_t ws_size,
                              hipStream_t stream)
{
    const float* x   = (const float*)d_in[0];
    const float* wq  = (const float*)d_in[1];
    const float* wk  = (const float*)d_in[2];
    const float* wv  = (const float*)d_in[3];
    const float* wo  = (const float*)d_in[4];
    const float* bo  = (const float*)d_in[5];
    const float* cw1 = (const float*)d_in[6];
    const float* cb1 = (const float*)d_in[7];
    const float* cw2 = (const float*)d_in[8];
    const float* cb2 = (const float*)d_in[9];
    const float* cw3 = (const float*)d_in[10];
    const float* cb3 = (const float*)d_in[11];
    float* out = (float*)d_out;

    char* ws = (char*)d_ws;
    const size_t MB = 1024 * 1024;
    bf16_t* xb    = (bf16_t*)(ws);             // 16 MB; reused as attention output
    bf16_t* wqkvb = (bf16_t*)(ws + 16 * MB);   // 6 MB   [3072][1024]
    bf16_t* wob   = (bf16_t*)(ws + 22 * MB);   // 2 MB
    bf16_t* QKV   = (bf16_t*)(ws + 24 * MB);   // 48 MB  [8192][3072]
    float*  conn  = (float*)(ws + 72 * MB);    // 448 B

    (void)hipFuncSetAttribute((const void*)gemm_fp<256, 128, DQKV, false, false>,
                              hipFuncAttributeMaxDynamicSharedMemorySize, 73728);
    (void)hipFuncSetAttribute((const void*)gemm_fp<128, 128, DM, true, true>,
                              hipFuncAttributeMaxDynamicSharedMemorySize, 49152);

    // all fp32->bf16 casts in one launch: 4096 (x) + 1536 (wqkv) + 512 (wo)
    fused_cast_kernel<<<6144, 256, 0, stream>>>(x, wq, wk, wv, wo, xb, wqkvb, wob);

    conn_kernel<<<NH, 32, 0, stream>>>(cw1, cb1, cw2, cb2, cw3, cb3, conn);

    // QKV: 32 M-tiles x 24 N-tiles = 768 blocks (2 blocks/CU)
    gemm_fp<256, 128, DQKV, false, false><<<768, 512, 73728, stream>>>(xb, wqkvb, QKV, nullptr);

    // attention: 1024 blocks (4/CU), LDS-staged K/V
    attn_win_kernel<<<NB * NH * (L_SEQ / LCH), 256, 0, stream>>>(QKV, conn, xb);

    // out-proj: 64 x 8 = 512 blocks
    gemm_fp<128, 128, DM, true, true><<<512, 512, 49152, stream>>>(xb, wob, out, bo);
}